// Round 4
// baseline (339.590 us; speedup 1.0000x reference)
//
#include <hip/hip_runtime.h>

#define N_NODES 100000
#define N_EDGES 600000
#define DIM 128
#define PAD 64   // max degree; deg ~ Poisson(6), P(>=64) ~ 1e-44 per node

// ---------------- edge_index dtype probe -------------------------------------
// Words at odd indices over the first 2*N_EDGES/2 words: int64 buffer -> all
// zero (high halves of values < 2^17); int32 buffer -> edge values (nonzero
// with certainty). flag==0 => int64, flag!=0 => int32.
__global__ __launch_bounds__(256) void detect_kernel(
    const unsigned* __restrict__ w, unsigned* __restrict__ flag) {
  unsigned v = 0;
  int stride = blockDim.x * gridDim.x;
  for (int i = blockIdx.x * blockDim.x + threadIdx.x; i < N_EDGES; i += stride)
    v |= w[2 * i + 1];   // stays within the smaller (int32) buffer: < 1.2M words
  unsigned long long b = __ballot(v != 0);
  if ((threadIdx.x & 63) == 0 && b) atomicOr(flag, 1u);
}

// ---------------- adjacency build: slot = atomicAdd(cursor[dst]) -------------
__global__ __launch_bounds__(256) void sage_fill(
    const int* __restrict__ ei32,
    const long long* __restrict__ ei64,
    const unsigned* __restrict__ flag,
    int* __restrict__ cursor,
    int* __restrict__ adj) {
  int e = blockIdx.x * blockDim.x + threadIdx.x;
  if (e >= N_EDGES) return;
  const bool i32 = (*flag != 0u);   // wave-uniform, L2-cached
  int s, d;
  if (i32) { s = ei32[e];       d = ei32[N_EDGES + e]; }
  else     { s = (int)ei64[e];  d = (int)ei64[N_EDGES + e]; }
  int slot = atomicAdd(&cursor[d], 1);
  if (slot < PAD) adj[(size_t)d * PAD + slot] = s;
}

// ---------------- pull aggregation: one wave per node ------------------------
__global__ __launch_bounds__(256) void sage_pull(
    const float* __restrict__ feat,
    const int* __restrict__ adj,
    const int* __restrict__ cursor,
    float* __restrict__ agg) {
  int node = blockIdx.x * (blockDim.x >> 6) + (threadIdx.x >> 6);
  if (node >= N_NODES) return;
  int lane = threadIdx.x & 63;
  int deg = cursor[node];              // wave-uniform
  int cnt = min(deg, PAD);
  const int* row = adj + (size_t)node * PAD;
  float ax = 0.f, ay = 0.f;
  for (int d = 0; d < cnt; d++) {
    int s = row[d];                    // wave-uniform
    float2 v = ((const float2*)(feat + (size_t)s * DIM))[lane];  // 512B coalesced
    ax += v.x; ay += v.y;
  }
  float inv = 1.0f / fmaxf((float)deg, 1.0f);
  ((float2*)(agg + (size_t)node * DIM))[lane] = make_float2(ax * inv, ay * inv);
}

// ---------------- fused GEMM: out = [agg | feat] @ [Wl | Wr]^T + bl ----------
#define BM 64
#define BN 128
#define BK 32
#define XLD (BM + 4)   // 68: b128 reads 2-way aliased (free per m136); 16B-aligned rows
#define WLD (BN + 4)   // 132

__global__ __launch_bounds__(256) void sage_gemm(
    const float* __restrict__ feat,
    const float* __restrict__ agg,    // pre-divided by degree
    const float* __restrict__ Wl,
    const float* __restrict__ bl,
    const float* __restrict__ Wr,
    float* __restrict__ out) {

  __shared__ float Xs[BK][XLD];
  __shared__ float Ws[BK][WLD];

  const int tid = threadIdx.x;
  const int brow = blockIdx.x * BM;

  const int r0 = (tid & 15) * 4;   // 4 consecutive rows
  const int c0 = (tid >> 4) * 8;   // 8 consecutive cols

  float acc[4][8];
#pragma unroll
  for (int i = 0; i < 4; i++)
#pragma unroll
    for (int j = 0; j < 8; j++) acc[i][j] = 0.f;

  for (int kb = 0; kb < 2 * DIM; kb += BK) {
    const bool isAgg = (kb < DIM);
    const int kglob = isAgg ? kb : kb - DIM;
    const float* __restrict__ Xsrc = isAgg ? agg : feat;
    const float* __restrict__ Wsrc = isAgg ? Wl : Wr;

#pragma unroll
    for (int j = 0; j < 8; j++) {
      int idx = j * 256 + tid;           // 0..2047
      int r = idx >> 5;
      int kk = idx & 31;
      int row = brow + r;
      Xs[kk][r] = (row < N_NODES) ? Xsrc[(size_t)row * DIM + kglob + kk] : 0.f;
    }
#pragma unroll
    for (int j = 0; j < 16; j++) {
      int idx = j * 256 + tid;           // 0..4095
      int d = idx >> 5;
      int kk = idx & 31;
      Ws[kk][d] = Wsrc[d * DIM + kglob + kk];
    }
    __syncthreads();

#pragma unroll
    for (int kk = 0; kk < BK; kk++) {
      float a[4], b[8];
      *(float4*)a = *(const float4*)&Xs[kk][r0];
      *(float4*)(b + 0) = *(const float4*)&Ws[kk][c0];
      *(float4*)(b + 4) = *(const float4*)&Ws[kk][c0 + 4];
#pragma unroll
      for (int i = 0; i < 4; i++)
#pragma unroll
        for (int j = 0; j < 8; j++) acc[i][j] = fmaf(a[i], b[j], acc[i][j]);
    }
    __syncthreads();
  }

  float bias[8];
#pragma unroll
  for (int j = 0; j < 8; j++) bias[j] = bl[c0 + j];

#pragma unroll
  for (int i = 0; i < 4; i++) {
    int row = brow + r0 + i;
    if (row < N_NODES) {
      float4 o0, o1;
      o0.x = acc[i][0] + bias[0]; o0.y = acc[i][1] + bias[1];
      o0.z = acc[i][2] + bias[2]; o0.w = acc[i][3] + bias[3];
      o1.x = acc[i][4] + bias[4]; o1.y = acc[i][5] + bias[5];
      o1.z = acc[i][6] + bias[6]; o1.w = acc[i][7] + bias[7];
      float* op = out + (size_t)row * DIM + c0;
      *(float4*)op = o0;
      *(float4*)(op + 4) = o1;
    }
  }
}

// ---------------- fallback path (small ws): f32 atomic scatter ---------------
__global__ __launch_bounds__(256) void sage_scatter(
    const float* __restrict__ feat,
    const int* __restrict__ ei32,
    const long long* __restrict__ ei64,
    const unsigned* __restrict__ flag,
    float* __restrict__ agg,
    float* __restrict__ deg,
    int nWaves) {
  int wave = (blockIdx.x * blockDim.x + threadIdx.x) >> 6;
  int lane = threadIdx.x & 63;
  const bool i32 = (*flag != 0u);
  for (int e = wave; e < N_EDGES; e += nWaves) {
    int s, d;
    if (i32) { s = ei32[e];      d = ei32[N_EDGES + e]; }
    else     { s = (int)ei64[e]; d = (int)ei64[N_EDGES + e]; }
    float2 v = ((const float2*)(feat + (size_t)s * DIM))[lane];
    float* a = agg + (size_t)d * DIM + lane * 2;
    unsafeAtomicAdd(a, v.x);
    unsafeAtomicAdd(a + 1, v.y);
    if (lane == 0) unsafeAtomicAdd(deg + d, 1.0f);
  }
}

__global__ __launch_bounds__(256) void sage_norm(
    float* __restrict__ agg, const float* __restrict__ deg) {
  int i = blockIdx.x * blockDim.x + threadIdx.x;
  if (i >= N_NODES * DIM) return;
  int n = i >> 7;
  agg[i] *= 1.0f / fmaxf(deg[n], 1.0f);
}

extern "C" void kernel_launch(void* const* d_in, const int* in_sizes, int n_in,
                              void* d_out, int out_size, void* d_ws, size_t ws_size,
                              hipStream_t stream) {
  const float* feat = (const float*)d_in[0];
  const int* ei32 = (const int*)d_in[1];
  const long long* ei64 = (const long long*)d_in[1];
  const unsigned* eiw = (const unsigned*)d_in[1];
  const float* Wl = (const float*)d_in[2];
  const float* bl = (const float*)d_in[3];
  const float* Wr = (const float*)d_in[4];
  float* out = (float*)d_out;

  // ws layout (pull): [flag pad x16 ints][cursor N][adj N*PAD][agg N*D floats]
  const size_t needPull = (16 + (size_t)N_NODES + (size_t)N_NODES * PAD) * 4
                        + (size_t)N_NODES * DIM * 4;

  if (ws_size >= needPull) {
    unsigned* flag = (unsigned*)d_ws;
    int* cursor = (int*)d_ws + 16;
    int* adj = cursor + N_NODES;
    float* agg = (float*)(adj + (size_t)N_NODES * PAD);
    hipMemsetAsync(d_ws, 0, (16 + (size_t)N_NODES) * 4, stream);
    detect_kernel<<<256, 256, 0, stream>>>(eiw, flag);
    sage_fill<<<(N_EDGES + 255) / 256, 256, 0, stream>>>(ei32, ei64, flag, cursor, adj);
    sage_pull<<<(N_NODES + 3) / 4, 256, 0, stream>>>(feat, adj, cursor, agg);
    sage_gemm<<<(N_NODES + BM - 1) / BM, 256, 0, stream>>>(feat, agg, Wl, bl, Wr, out);
  } else {
    unsigned* flag = (unsigned*)d_ws;
    float* agg = (float*)d_ws + 16;
    float* deg = agg + (size_t)N_NODES * DIM;
    hipMemsetAsync(d_ws, 0, (16 + (size_t)N_NODES * DIM + N_NODES) * 4, stream);
    detect_kernel<<<256, 256, 0, stream>>>(eiw, flag);
    const int sblocks = 2048;
    sage_scatter<<<sblocks, 256, 0, stream>>>(feat, ei32, ei64, flag, agg, deg, sblocks * 4);
    sage_norm<<<(N_NODES * DIM + 255) / 256, 256, 0, stream>>>(agg, deg);
    sage_gemm<<<(N_NODES + BM - 1) / BM, 256, 0, stream>>>(feat, agg, Wl, bl, Wr, out);
  }
}

// Round 6
// 290.214 us; speedup vs baseline: 1.1701x; 1.1701x over previous
//
#include <hip/hip_runtime.h>

#define N_NODES 100000
#define N_EDGES 600000
#define DIM 128
#define PAD 64   // max degree; deg ~ Poisson(6), max over 100k nodes ~ 24

// ---------------- edge_index dtype probe -------------------------------------
// int64 buffer -> odd 32-bit words all zero (values < 2^17); int32 -> nonzero.
__global__ __launch_bounds__(256) void detect_kernel(
    const unsigned* __restrict__ w, unsigned* __restrict__ flag) {
  unsigned v = 0;
  int stride = blockDim.x * gridDim.x;
  for (int i = blockIdx.x * blockDim.x + threadIdx.x; i < N_EDGES; i += stride)
    v |= w[2 * i + 1];
  unsigned long long b = __ballot(v != 0);
  if ((threadIdx.x & 63) == 0 && b) atomicOr(flag, 1u);
}

// ---------------- adjacency build: slot = atomicAdd(cursor[dst]) -------------
__global__ __launch_bounds__(256) void sage_fill(
    const int* __restrict__ ei32,
    const long long* __restrict__ ei64,
    const unsigned* __restrict__ flag,
    int* __restrict__ cursor,
    int* __restrict__ adj) {
  int e = blockIdx.x * blockDim.x + threadIdx.x;
  if (e >= N_EDGES) return;
  const bool i32 = (*flag != 0u);
  int s, d;
  if (i32) { s = ei32[e];       d = ei32[N_EDGES + e]; }
  else     { s = (int)ei64[e];  d = (int)ei64[N_EDGES + e]; }
  int slot = atomicAdd(&cursor[d], 1);
  if (slot < PAD) adj[(size_t)d * PAD + slot] = s;
}

// ---------------- pull aggregation: HALF-WAVE (32 lanes) per node ------------
// Lane holds float4 (32 lanes x 16B = 512B row). Neighbor ids loaded once as a
// 32-wide vector load, broadcast per-iteration via __shfl(.,d,32).
__global__ __launch_bounds__(256) void sage_pull(
    const float* __restrict__ feat,
    const int* __restrict__ adj,
    const int* __restrict__ cursor,
    float* __restrict__ agg) {
  int node = blockIdx.x * 8 + (threadIdx.x >> 5);
  if (node >= N_NODES) return;
  int hl = threadIdx.x & 31;
  int deg = cursor[node];              // uniform per half-wave
  int cnt = min(deg, PAD);
  const int* __restrict__ row = adj + (size_t)node * PAD;
  int sv = row[hl];                    // 32 slots; beyond cnt unused (poison ok)
  float ax = 0.f, ay = 0.f, az = 0.f, aw = 0.f;
  int iter = min(cnt, 32);
  for (int d = 0; d < iter; ++d) {
    int s = __shfl(sv, d, 32);
    float4 v = ((const float4*)(feat + (size_t)s * DIM))[hl];
    ax += v.x; ay += v.y; az += v.z; aw += v.w;
  }
  if (cnt > 32) {                      // astronomically cold, exactness guard
    for (int d = 32; d < cnt; ++d) {
      int s = row[d];
      float4 v = ((const float4*)(feat + (size_t)s * DIM))[hl];
      ax += v.x; ay += v.y; az += v.z; aw += v.w;
    }
  }
  float inv = 1.0f / fmaxf((float)deg, 1.0f);
  ((float4*)(agg + (size_t)node * DIM))[hl] =
      make_float4(ax * inv, ay * inv, az * inv, aw * inv);
}

// ---------------- fused GEMM: out = [agg | feat] @ [Wl | Wr]^T + bl ----------
// BM=128, BN=128, BK=32, 256 threads, 8x8 microtile as 2x2 blocks of 4x4 at
// row/col offsets {0,+64} (keeps ds_read_b128 at 16B lane-stride: conflict-free).
#define BM 128
#define BN 128
#define BK 32
#define XLD (BM + 4)   // 132 floats: 528B rows, 16B-aligned
#define WLD (BN + 4)

__global__ __launch_bounds__(256) void sage_gemm(
    const float* __restrict__ feat,
    const float* __restrict__ agg,    // pre-divided by degree
    const float* __restrict__ Wl,
    const float* __restrict__ bl,
    const float* __restrict__ Wr,
    float* __restrict__ out) {

  __shared__ float Xs[BK][XLD];
  __shared__ float Ws[BK][WLD];

  const int tid = threadIdx.x;
  const int brow = blockIdx.x * BM;

  const int r0 = (tid & 15) * 4;   // rows r0..r0+3 and r0+64..r0+67
  const int c0 = (tid >> 4) * 4;   // cols c0..c0+3 and c0+64..c0+67

  float acc[8][8];
#pragma unroll
  for (int i = 0; i < 8; i++)
#pragma unroll
    for (int j = 0; j < 8; j++) acc[i][j] = 0.f;

  for (int kb = 0; kb < 2 * DIM; kb += BK) {
    const bool isAgg = (kb < DIM);
    const int kglob = isAgg ? kb : kb - DIM;
    const float* __restrict__ Xsrc = isAgg ? agg : feat;
    const float* __restrict__ Wsrc = isAgg ? Wl : Wr;

    // stage X tile transposed via float4 global reads (8 lanes = 128B / row)
#pragma unroll
    for (int j = 0; j < 4; j++) {
      int f4 = j * 256 + tid;          // 0..1023
      int r = f4 >> 3;                 // 0..127
      int k4 = (f4 & 7) * 4;           // 0,4,..,28
      int row = brow + r;
      float4 v = make_float4(0.f, 0.f, 0.f, 0.f);
      if (row < N_NODES) v = *(const float4*)&Xsrc[(size_t)row * DIM + kglob + k4];
      Xs[k4 + 0][r] = v.x; Xs[k4 + 1][r] = v.y;
      Xs[k4 + 2][r] = v.z; Xs[k4 + 3][r] = v.w;
    }
    // stage W tile transposed
#pragma unroll
    for (int j = 0; j < 4; j++) {
      int f4 = j * 256 + tid;
      int d = f4 >> 3;                 // 0..127 (output col)
      int k4 = (f4 & 7) * 4;
      float4 v = *(const float4*)&Wsrc[(size_t)d * DIM + kglob + k4];
      Ws[k4 + 0][d] = v.x; Ws[k4 + 1][d] = v.y;
      Ws[k4 + 2][d] = v.z; Ws[k4 + 3][d] = v.w;
    }
    __syncthreads();

#pragma unroll 8
    for (int kk = 0; kk < BK; kk++) {
      float4 a0 = *(const float4*)&Xs[kk][r0];
      float4 a1 = *(const float4*)&Xs[kk][r0 + 64];
      float4 b0 = *(const float4*)&Ws[kk][c0];
      float4 b1 = *(const float4*)&Ws[kk][c0 + 64];
      float a[8] = {a0.x, a0.y, a0.z, a0.w, a1.x, a1.y, a1.z, a1.w};
      float b[8] = {b0.x, b0.y, b0.z, b0.w, b1.x, b1.y, b1.z, b1.w};
#pragma unroll
      for (int i = 0; i < 8; i++)
#pragma unroll
        for (int j = 0; j < 8; j++) acc[i][j] = fmaf(a[i], b[j], acc[i][j]);
    }
    __syncthreads();
  }

  float4 bias0 = *(const float4*)&bl[c0];
  float4 bias1 = *(const float4*)&bl[c0 + 64];
  float bb[8] = {bias0.x, bias0.y, bias0.z, bias0.w,
                 bias1.x, bias1.y, bias1.z, bias1.w};

#pragma unroll
  for (int i = 0; i < 8; i++) {
    int row = brow + ((i < 4) ? (r0 + i) : (64 + r0 + i - 4));
    if (row < N_NODES) {
      float* op = out + (size_t)row * DIM;
      float4 o0, o1;
      o0.x = acc[i][0] + bb[0]; o0.y = acc[i][1] + bb[1];
      o0.z = acc[i][2] + bb[2]; o0.w = acc[i][3] + bb[3];
      o1.x = acc[i][4] + bb[4]; o1.y = acc[i][5] + bb[5];
      o1.z = acc[i][6] + bb[6]; o1.w = acc[i][7] + bb[7];
      *(float4*)(op + c0) = o0;
      *(float4*)(op + c0 + 64) = o1;
    }
  }
}

// ---------------- fallback path (small ws): f32 atomic scatter ---------------
__global__ __launch_bounds__(256) void sage_scatter(
    const float* __restrict__ feat,
    const int* __restrict__ ei32,
    const long long* __restrict__ ei64,
    const unsigned* __restrict__ flag,
    float* __restrict__ agg,
    float* __restrict__ deg,
    int nWaves) {
  int wave = (blockIdx.x * blockDim.x + threadIdx.x) >> 6;
  int lane = threadIdx.x & 63;
  const bool i32 = (*flag != 0u);
  for (int e = wave; e < N_EDGES; e += nWaves) {
    int s, d;
    if (i32) { s = ei32[e];      d = ei32[N_EDGES + e]; }
    else     { s = (int)ei64[e]; d = (int)ei64[N_EDGES + e]; }
    float2 v = ((const float2*)(feat + (size_t)s * DIM))[lane];
    float* a = agg + (size_t)d * DIM + lane * 2;
    unsafeAtomicAdd(a, v.x);
    unsafeAtomicAdd(a + 1, v.y);
    if (lane == 0) unsafeAtomicAdd(deg + d, 1.0f);
  }
}

__global__ __launch_bounds__(256) void sage_norm(
    float* __restrict__ agg, const float* __restrict__ deg) {
  int i = blockIdx.x * blockDim.x + threadIdx.x;
  if (i >= N_NODES * DIM) return;
  int n = i >> 7;
  agg[i] *= 1.0f / fmaxf(deg[n], 1.0f);
}

extern "C" void kernel_launch(void* const* d_in, const int* in_sizes, int n_in,
                              void* d_out, int out_size, void* d_ws, size_t ws_size,
                              hipStream_t stream) {
  const float* feat = (const float*)d_in[0];
  const int* ei32 = (const int*)d_in[1];
  const long long* ei64 = (const long long*)d_in[1];
  const unsigned* eiw = (const unsigned*)d_in[1];
  const float* Wl = (const float*)d_in[2];
  const float* bl = (const float*)d_in[3];
  const float* Wr = (const float*)d_in[4];
  float* out = (float*)d_out;

  const size_t needPull = (16 + (size_t)N_NODES + (size_t)N_NODES * PAD) * 4
                        + (size_t)N_NODES * DIM * 4;

  const int gblocks = (N_NODES + BM - 1) / BM;   // 782

  if (ws_size >= needPull) {
    unsigned* flag = (unsigned*)d_ws;
    int* cursor = (int*)d_ws + 16;
    int* adj = cursor + N_NODES;
    float* agg = (float*)(adj + (size_t)N_NODES * PAD);
    hipMemsetAsync(d_ws, 0, (16 + (size_t)N_NODES) * 4, stream);
    detect_kernel<<<256, 256, 0, stream>>>(eiw, flag);
    sage_fill<<<(N_EDGES + 255) / 256, 256, 0, stream>>>(ei32, ei64, flag, cursor, adj);
    sage_pull<<<(N_NODES + 7) / 8, 256, 0, stream>>>(feat, adj, cursor, agg);
    sage_gemm<<<gblocks, 256, 0, stream>>>(feat, agg, Wl, bl, Wr, out);
  } else {
    unsigned* flag = (unsigned*)d_ws;
    float* agg = (float*)d_ws + 16;
    float* deg = agg + (size_t)N_NODES * DIM;
    hipMemsetAsync(d_ws, 0, (16 + (size_t)N_NODES * DIM + N_NODES) * 4, stream);
    detect_kernel<<<256, 256, 0, stream>>>(eiw, flag);
    const int sblocks = 2048;
    sage_scatter<<<sblocks, 256, 0, stream>>>(feat, ei32, ei64, flag, agg, deg, sblocks * 4);
    sage_norm<<<(N_NODES * DIM + 255) / 256, 256, 0, stream>>>(agg, deg);
    sage_gemm<<<gblocks, 256, 0, stream>>>(feat, agg, Wl, bl, Wr, out);
  }
}

// Round 7
// 280.296 us; speedup vs baseline: 1.2115x; 1.0354x over previous
//
#include <hip/hip_runtime.h>

#define N_NODES 100000
#define N_EDGES 600000
#define DIM 128
#define PAD 64   // max degree; deg ~ Poisson(6), max over 100k nodes ~ 24

// ---------------- edge_index dtype probe (1 block) ---------------------------
// int64 buffer -> odd 32-bit words all zero (values < 2^17); int32 -> edge
// values at odd indices. 2048 samples: P(all zero | int32) = (1e-5)^2048 = 0.
__global__ __launch_bounds__(256) void detect_kernel(
    const unsigned* __restrict__ w, unsigned* __restrict__ flag) {
  unsigned v = 0;
  for (int i = threadIdx.x; i < 2048; i += 256) v |= w[2 * i + 1];
  unsigned long long b = __ballot(v != 0);
  if ((threadIdx.x & 63) == 0 && b) atomicOr(flag, 1u);
}

// ---------------- adjacency build: slot = atomicAdd(cursor[dst]) -------------
__global__ __launch_bounds__(256) void sage_fill(
    const int* __restrict__ ei32,
    const long long* __restrict__ ei64,
    const unsigned* __restrict__ flag,
    int* __restrict__ cursor,
    int* __restrict__ adj) {
  int e = blockIdx.x * blockDim.x + threadIdx.x;
  if (e >= N_EDGES) return;
  const bool i32 = (*flag != 0u);
  int s, d;
  if (i32) { s = ei32[e];       d = ei32[N_EDGES + e]; }
  else     { s = (int)ei64[e];  d = (int)ei64[N_EDGES + e]; }
  int slot = atomicAdd(&cursor[d], 1);
  if (slot < PAD) adj[(size_t)d * PAD + slot] = s;
}

// ---------------- pull aggregation: HALF-WAVE (32 lanes) per node ------------
// Lane holds float4 (32 lanes x 16B = 512B row). Neighbor ids loaded once,
// broadcast via __shfl; gathers issued in pairs for MLP.
__global__ __launch_bounds__(256) void sage_pull(
    const float* __restrict__ feat,
    const int* __restrict__ adj,
    const int* __restrict__ cursor,
    float* __restrict__ agg) {
  int node = blockIdx.x * 8 + (threadIdx.x >> 5);
  if (node >= N_NODES) return;
  int hl = threadIdx.x & 31;
  int deg = cursor[node];              // uniform per half-wave
  int cnt = min(deg, PAD);
  const int* __restrict__ row = adj + (size_t)node * PAD;
  int sv = row[hl];                    // 32 slots; beyond cnt unused (poison ok)
  float ax = 0.f, ay = 0.f, az = 0.f, aw = 0.f;
  int iter = min(cnt, 32);
  int d = 0;
  for (; d + 1 < iter; d += 2) {       // 2 outstanding gathers
    int s0 = __shfl(sv, d, 32);
    int s1 = __shfl(sv, d + 1, 32);
    float4 v0 = ((const float4*)(feat + (size_t)s0 * DIM))[hl];
    float4 v1 = ((const float4*)(feat + (size_t)s1 * DIM))[hl];
    ax += v0.x; ay += v0.y; az += v0.z; aw += v0.w;
    ax += v1.x; ay += v1.y; az += v1.z; aw += v1.w;
  }
  if (d < iter) {
    int s = __shfl(sv, d, 32);
    float4 v = ((const float4*)(feat + (size_t)s * DIM))[hl];
    ax += v.x; ay += v.y; az += v.z; aw += v.w;
  }
  if (cnt > 32) {                      // astronomically cold, exactness guard
    for (int k = 32; k < cnt; ++k) {
      int s = row[k];
      float4 v = ((const float4*)(feat + (size_t)s * DIM))[hl];
      ax += v.x; ay += v.y; az += v.z; aw += v.w;
    }
  }
  float inv = 1.0f / fmaxf((float)deg, 1.0f);
  ((float4*)(agg + (size_t)node * DIM))[hl] =
      make_float4(ax * inv, ay * inv, az * inv, aw * inv);
}

// ---------------- fused GEMM: out = [agg | feat] @ [Wl | Wr]^T + bl ----------
// BM=128, BN=128, BK=32, 256 threads, 8x8 microtile as 2x2 blocks of 4x4 at
// row/col offsets {0,+64}. __launch_bounds__(256,2): let acc[8][8] live in
// VGPRs (round-6 showed VGPR capped at 64 -> accumulator shuffling).
#define BM 128
#define BN 128
#define BK 32
#define XLD (BM + 4)   // 132 floats: 528B rows, 16B-aligned
#define WLD (BN + 4)

__global__ __launch_bounds__(256, 2) void sage_gemm(
    const float* __restrict__ feat,
    const float* __restrict__ agg,    // pre-divided by degree
    const float* __restrict__ Wl,
    const float* __restrict__ bl,
    const float* __restrict__ Wr,
    float* __restrict__ out) {

  __shared__ float Xs[BK][XLD];
  __shared__ float Ws[BK][WLD];

  const int tid = threadIdx.x;
  const int brow = blockIdx.x * BM;

  const int r0 = (tid & 15) * 4;   // rows r0..r0+3 and r0+64..r0+67
  const int c0 = (tid >> 4) * 4;   // cols c0..c0+3 and c0+64..c0+67

  float acc[8][8];
#pragma unroll
  for (int i = 0; i < 8; i++)
#pragma unroll
    for (int j = 0; j < 8; j++) acc[i][j] = 0.f;

  for (int kb = 0; kb < 2 * DIM; kb += BK) {
    const bool isAgg = (kb < DIM);
    const int kglob = isAgg ? kb : kb - DIM;
    const float* __restrict__ Xsrc = isAgg ? agg : feat;
    const float* __restrict__ Wsrc = isAgg ? Wl : Wr;

    // stage X tile transposed via float4 global reads (8 lanes = 128B / row)
#pragma unroll
    for (int j = 0; j < 4; j++) {
      int f4 = j * 256 + tid;          // 0..1023
      int r = f4 >> 3;                 // 0..127
      int k4 = (f4 & 7) * 4;           // 0,4,..,28
      int row = brow + r;
      float4 v = make_float4(0.f, 0.f, 0.f, 0.f);
      if (row < N_NODES) v = *(const float4*)&Xsrc[(size_t)row * DIM + kglob + k4];
      Xs[k4 + 0][r] = v.x; Xs[k4 + 1][r] = v.y;
      Xs[k4 + 2][r] = v.z; Xs[k4 + 3][r] = v.w;
    }
    // stage W tile transposed
#pragma unroll
    for (int j = 0; j < 4; j++) {
      int f4 = j * 256 + tid;
      int d = f4 >> 3;                 // 0..127 (output col)
      int k4 = (f4 & 7) * 4;
      float4 v = *(const float4*)&Wsrc[(size_t)d * DIM + kglob + k4];
      Ws[k4 + 0][d] = v.x; Ws[k4 + 1][d] = v.y;
      Ws[k4 + 2][d] = v.z; Ws[k4 + 3][d] = v.w;
    }
    __syncthreads();

#pragma unroll 8
    for (int kk = 0; kk < BK; kk++) {
      float4 a0 = *(const float4*)&Xs[kk][r0];
      float4 a1 = *(const float4*)&Xs[kk][r0 + 64];
      float4 b0 = *(const float4*)&Ws[kk][c0];
      float4 b1 = *(const float4*)&Ws[kk][c0 + 64];
      float a[8] = {a0.x, a0.y, a0.z, a0.w, a1.x, a1.y, a1.z, a1.w};
      float b[8] = {b0.x, b0.y, b0.z, b0.w, b1.x, b1.y, b1.z, b1.w};
#pragma unroll
      for (int i = 0; i < 8; i++)
#pragma unroll
        for (int j = 0; j < 8; j++) acc[i][j] = fmaf(a[i], b[j], acc[i][j]);
    }
    __syncthreads();
  }

  float4 bias0 = *(const float4*)&bl[c0];
  float4 bias1 = *(const float4*)&bl[c0 + 64];
  float bb[8] = {bias0.x, bias0.y, bias0.z, bias0.w,
                 bias1.x, bias1.y, bias1.z, bias1.w};

#pragma unroll
  for (int i = 0; i < 8; i++) {
    int row = brow + ((i < 4) ? (r0 + i) : (64 + r0 + i - 4));
    if (row < N_NODES) {
      float* op = out + (size_t)row * DIM;
      float4 o0, o1;
      o0.x = acc[i][0] + bb[0]; o0.y = acc[i][1] + bb[1];
      o0.z = acc[i][2] + bb[2]; o0.w = acc[i][3] + bb[3];
      o1.x = acc[i][4] + bb[4]; o1.y = acc[i][5] + bb[5];
      o1.z = acc[i][6] + bb[6]; o1.w = acc[i][7] + bb[7];
      *(float4*)(op + c0) = o0;
      *(float4*)(op + c0 + 64) = o1;
    }
  }
}

// ---------------- fallback path (small ws): f32 atomic scatter ---------------
__global__ __launch_bounds__(256) void sage_scatter(
    const float* __restrict__ feat,
    const int* __restrict__ ei32,
    const long long* __restrict__ ei64,
    const unsigned* __restrict__ flag,
    float* __restrict__ agg,
    float* __restrict__ deg,
    int nWaves) {
  int wave = (blockIdx.x * blockDim.x + threadIdx.x) >> 6;
  int lane = threadIdx.x & 63;
  const bool i32 = (*flag != 0u);
  for (int e = wave; e < N_EDGES; e += nWaves) {
    int s, d;
    if (i32) { s = ei32[e];      d = ei32[N_EDGES + e]; }
    else     { s = (int)ei64[e]; d = (int)ei64[N_EDGES + e]; }
    float2 v = ((const float2*)(feat + (size_t)s * DIM))[lane];
    float* a = agg + (size_t)d * DIM + lane * 2;
    unsafeAtomicAdd(a, v.x);
    unsafeAtomicAdd(a + 1, v.y);
    if (lane == 0) unsafeAtomicAdd(deg + d, 1.0f);
  }
}

__global__ __launch_bounds__(256) void sage_norm(
    float* __restrict__ agg, const float* __restrict__ deg) {
  int i = blockIdx.x * blockDim.x + threadIdx.x;
  if (i >= N_NODES * DIM) return;
  int n = i >> 7;
  agg[i] *= 1.0f / fmaxf(deg[n], 1.0f);
}

extern "C" void kernel_launch(void* const* d_in, const int* in_sizes, int n_in,
                              void* d_out, int out_size, void* d_ws, size_t ws_size,
                              hipStream_t stream) {
  const float* feat = (const float*)d_in[0];
  const int* ei32 = (const int*)d_in[1];
  const long long* ei64 = (const long long*)d_in[1];
  const unsigned* eiw = (const unsigned*)d_in[1];
  const float* Wl = (const float*)d_in[2];
  const float* bl = (const float*)d_in[3];
  const float* Wr = (const float*)d_in[4];
  float* out = (float*)d_out;

  const size_t needPull = (16 + (size_t)N_NODES + (size_t)N_NODES * PAD) * 4
                        + (size_t)N_NODES * DIM * 4;

  const int gblocks = (N_NODES + BM - 1) / BM;   // 782

  if (ws_size >= needPull) {
    unsigned* flag = (unsigned*)d_ws;
    int* cursor = (int*)d_ws + 16;
    int* adj = cursor + N_NODES;
    float* agg = (float*)(adj + (size_t)N_NODES * PAD);
    hipMemsetAsync(d_ws, 0, (16 + (size_t)N_NODES) * 4, stream);
    detect_kernel<<<1, 256, 0, stream>>>(eiw, flag);
    sage_fill<<<(N_EDGES + 255) / 256, 256, 0, stream>>>(ei32, ei64, flag, cursor, adj);
    sage_pull<<<(N_NODES + 7) / 8, 256, 0, stream>>>(feat, adj, cursor, agg);
    sage_gemm<<<gblocks, 256, 0, stream>>>(feat, agg, Wl, bl, Wr, out);
  } else {
    unsigned* flag = (unsigned*)d_ws;
    float* agg = (float*)d_ws + 16;
    float* deg = agg + (size_t)N_NODES * DIM;
    hipMemsetAsync(d_ws, 0, (16 + (size_t)N_NODES * DIM + N_NODES) * 4, stream);
    detect_kernel<<<1, 256, 0, stream>>>(eiw, flag);
    const int sblocks = 2048;
    sage_scatter<<<sblocks, 256, 0, stream>>>(feat, ei32, ei64, flag, agg, deg, sblocks * 4);
    sage_norm<<<(N_NODES * DIM + 255) / 256, 256, 0, stream>>>(agg, deg);
    sage_gemm<<<gblocks, 256, 0, stream>>>(feat, agg, Wl, bl, Wr, out);
  }
}

// Round 9
// 230.689 us; speedup vs baseline: 1.4721x; 1.2150x over previous
//
#include <hip/hip_runtime.h>

#define N_NODES 100000
#define N_EDGES 600000
#define DIM 128
#define PAD 64   // max degree; deg ~ Poisson(6), max over 100k nodes ~ 24

typedef __attribute__((ext_vector_type(8))) short short8;   // 8 bf16 (4 VGPRs)
typedef __attribute__((ext_vector_type(4))) float f32x4;

// ---------------- edge_index dtype probe (1 block) ---------------------------
// int64 buffer -> odd 32-bit words all zero (values < 2^17); int32 -> edge
// values at odd indices. 2048 samples: P(all zero | int32) = 0.
__global__ __launch_bounds__(256) void detect_kernel(
    const unsigned* __restrict__ w, unsigned* __restrict__ flag) {
  unsigned v = 0;
  for (int i = threadIdx.x; i < 2048; i += 256) v |= w[2 * i + 1];
  unsigned long long b = __ballot(v != 0);
  if ((threadIdx.x & 63) == 0 && b) atomicOr(flag, 1u);
}

// ---------------- adjacency build: slot = atomicAdd(cursor[dst]) -------------
__global__ __launch_bounds__(256) void sage_fill(
    const int* __restrict__ ei32,
    const long long* __restrict__ ei64,
    const unsigned* __restrict__ flag,
    int* __restrict__ cursor,
    int* __restrict__ adj) {
  int e = blockIdx.x * blockDim.x + threadIdx.x;
  if (e >= N_EDGES) return;
  const bool i32 = (*flag != 0u);
  int s, d;
  if (i32) { s = ei32[e];       d = ei32[N_EDGES + e]; }
  else     { s = (int)ei64[e];  d = (int)ei64[N_EDGES + e]; }
  int slot = atomicAdd(&cursor[d], 1);
  if (slot < PAD) adj[(size_t)d * PAD + slot] = s;
}

// ---------------- pull aggregation: HALF-WAVE (32 lanes) per node ------------
__global__ __launch_bounds__(256) void sage_pull(
    const float* __restrict__ feat,
    const int* __restrict__ adj,
    const int* __restrict__ cursor,
    float* __restrict__ agg) {
  int node = blockIdx.x * 8 + (threadIdx.x >> 5);
  if (node >= N_NODES) return;
  int hl = threadIdx.x & 31;
  int deg = cursor[node];              // uniform per half-wave
  int cnt = min(deg, PAD);
  const int* __restrict__ row = adj + (size_t)node * PAD;
  int sv = row[hl];
  float ax = 0.f, ay = 0.f, az = 0.f, aw = 0.f;
  int iter = min(cnt, 32);
  int d = 0;
  for (; d + 1 < iter; d += 2) {       // 2 outstanding gathers
    int s0 = __shfl(sv, d, 32);
    int s1 = __shfl(sv, d + 1, 32);
    float4 v0 = ((const float4*)(feat + (size_t)s0 * DIM))[hl];
    float4 v1 = ((const float4*)(feat + (size_t)s1 * DIM))[hl];
    ax += v0.x; ay += v0.y; az += v0.z; aw += v0.w;
    ax += v1.x; ay += v1.y; az += v1.z; aw += v1.w;
  }
  if (d < iter) {
    int s = __shfl(sv, d, 32);
    float4 v = ((const float4*)(feat + (size_t)s * DIM))[hl];
    ax += v.x; ay += v.y; az += v.z; aw += v.w;
  }
  if (cnt > 32) {
    for (int k = 32; k < cnt; ++k) {
      int s = row[k];
      float4 v = ((const float4*)(feat + (size_t)s * DIM))[hl];
      ax += v.x; ay += v.y; az += v.z; aw += v.w;
    }
  }
  float inv = 1.0f / fmaxf((float)deg, 1.0f);
  ((float4*)(agg + (size_t)node * DIM))[hl] =
      make_float4(ax * inv, ay * inv, az * inv, aw * inv);
}

// ---------------- bf16x3-split MFMA GEMM -------------------------------------
// out = [agg | feat] @ [Wl | Wr]^T + bl,  K=256 total, via x=xh+xl, w=wh+wl:
// acc += xh*wh + xh*wl + xl*wh  (xl*wl ~2^-16 rel, dropped).
// Block: 256 thr = 4 waves, tile 128x128, BK=64. Wave tile 64x64 = 4x4 frags
// of mfma_f32_16x16x32_bf16. LDS bf16 tiles XOR-swizzled: ushort idx =
// row*64 + (k ^ ((row&7)<<3))  (kills stride-128B bank conflicts; b128-aligned
// since swizzle touches bits 3-5 only).
#define GBM 128
#define GBK 64

__device__ __forceinline__ unsigned bf16_rne_hi(float x) {
  unsigned u = __float_as_uint(x);
  return (u + 0x7FFFu + ((u >> 16) & 1u)) & 0xFFFF0000u;  // bf16(x) in high 16
}

__global__ __launch_bounds__(256, 2) void sage_gemm_mfma(
    const float* __restrict__ feat,
    const float* __restrict__ agg,    // pre-divided by degree
    const float* __restrict__ Wl,
    const float* __restrict__ bl,
    const float* __restrict__ Wr,
    float* __restrict__ out) {

  __shared__ ushort XhL[GBM * GBK];   // 16 KB each; 64 KB total
  __shared__ ushort XlL[GBM * GBK];
  __shared__ ushort WhL[DIM * GBK];
  __shared__ ushort WloL[DIM * GBK];

  const int tid = threadIdx.x;
  const int brow = blockIdx.x * GBM;
  const int w = tid >> 6;
  const int lane = tid & 63;
  const int l15 = lane & 15;
  const int lgrp = lane >> 4;          // 0..3
  const int wr = (w >> 1) * 64;        // wave row offset in tile
  const int wc = (w & 1) * 64;         // wave col offset

  f32x4 acc[4][4];
#pragma unroll
  for (int i = 0; i < 4; i++)
#pragma unroll
    for (int j = 0; j < 4; j++) acc[i][j] = (f32x4){0.f, 0.f, 0.f, 0.f};

  for (int kb = 0; kb < 4; kb++) {     // kb 0,1: agg/Wl; 2,3: feat/Wr
    const float* __restrict__ Xsrc = (kb < 2) ? agg : feat;
    const float* __restrict__ Wsrc = (kb < 2) ? Wl : Wr;
    const int koff = (kb & 1) * GBK;

    __syncthreads();                   // prev compute done before overwrite
    // stage X tile: 128 rows x 64 k, f32 -> bf16 hi/lo
#pragma unroll
    for (int i = 0; i < 8; i++) {
      int f4 = i * 256 + tid;          // 0..2047
      int r = f4 >> 4;                 // 0..127
      int k4 = (f4 & 15) * 4;          // 0..60
      int grow = brow + r;
      float4 v = make_float4(0.f, 0.f, 0.f, 0.f);
      if (grow < N_NODES) v = *(const float4*)&Xsrc[(size_t)grow * DIM + koff + k4];
      unsigned h0 = bf16_rne_hi(v.x), h1 = bf16_rne_hi(v.y);
      unsigned h2 = bf16_rne_hi(v.z), h3 = bf16_rne_hi(v.w);
      float lx = v.x - __uint_as_float(h0);
      float ly = v.y - __uint_as_float(h1);
      float lz = v.z - __uint_as_float(h2);
      float lw = v.w - __uint_as_float(h3);
      uint2 hp, lp;
      hp.x = (h0 >> 16) | h1;
      hp.y = (h2 >> 16) | h3;
      lp.x = (__float_as_uint(lx) >> 16) | (__float_as_uint(ly) & 0xFFFF0000u);
      lp.y = (__float_as_uint(lz) >> 16) | (__float_as_uint(lw) & 0xFFFF0000u);
      int idx = r * GBK + (k4 ^ ((r & 7) << 3));
      *(uint2*)&XhL[idx] = hp;
      *(uint2*)&XlL[idx] = lp;
    }
    // stage W tile: 128 out-cols x 64 k (W is [out][k] row-major: straight copy)
#pragma unroll
    for (int i = 0; i < 8; i++) {
      int f4 = i * 256 + tid;
      int c = f4 >> 4;
      int k4 = (f4 & 15) * 4;
      float4 v = *(const float4*)&Wsrc[(size_t)c * DIM + koff + k4];
      unsigned h0 = bf16_rne_hi(v.x), h1 = bf16_rne_hi(v.y);
      unsigned h2 = bf16_rne_hi(v.z), h3 = bf16_rne_hi(v.w);
      float lx = v.x - __uint_as_float(h0);
      float ly = v.y - __uint_as_float(h1);
      float lz = v.z - __uint_as_float(h2);
      float lw = v.w - __uint_as_float(h3);
      uint2 hp, lp;
      hp.x = (h0 >> 16) | h1;
      hp.y = (h2 >> 16) | h3;
      lp.x = (__float_as_uint(lx) >> 16) | (__float_as_uint(ly) & 0xFFFF0000u);
      lp.y = (__float_as_uint(lz) >> 16) | (__float_as_uint(lw) & 0xFFFF0000u);
      int idx = c * GBK + (k4 ^ ((c & 7) << 3));
      *(uint2*)&WhL[idx] = hp;
      *(uint2*)&WloL[idx] = lp;
    }
    __syncthreads();

#pragma unroll
    for (int ks = 0; ks < 2; ks++) {   // two K=32 steps per BK=64
      const int k0 = ks * 32 + lgrp * 8;
      short8 ah[4], al[4], bh[4], blo[4];
#pragma unroll
      for (int f = 0; f < 4; f++) {
        int ar = wr + f * 16 + l15;    // A: row = lane&15 (+frag), k = lgrp*8+j
        int aidx = ar * GBK + (k0 ^ ((ar & 7) << 3));
        ah[f] = *(const short8*)&XhL[aidx];
        al[f] = *(const short8*)&XlL[aidx];
        int bc = wc + f * 16 + l15;    // B: col = lane&15 (+frag), same k
        int bidx = bc * GBK + (k0 ^ ((bc & 7) << 3));
        bh[f] = *(const short8*)&WhL[bidx];
        blo[f] = *(const short8*)&WloL[bidx];
      }
#pragma unroll
      for (int fi = 0; fi < 4; fi++)
#pragma unroll
        for (int fj = 0; fj < 4; fj++) {
          acc[fi][fj] = __builtin_amdgcn_mfma_f32_16x16x32_bf16(
              ah[fi], bh[fj], acc[fi][fj], 0, 0, 0);
          acc[fi][fj] = __builtin_amdgcn_mfma_f32_16x16x32_bf16(
              ah[fi], blo[fj], acc[fi][fj], 0, 0, 0);
          acc[fi][fj] = __builtin_amdgcn_mfma_f32_16x16x32_bf16(
              al[fi], bh[fj], acc[fi][fj], 0, 0, 0);
        }
    }
  }

  // epilogue: C/D layout col=lane&15, row=(lane>>4)*4+reg (m89-verified)
  float bias[4];
#pragma unroll
  for (int fj = 0; fj < 4; fj++) bias[fj] = bl[wc + fj * 16 + l15];

#pragma unroll
  for (int fi = 0; fi < 4; fi++) {
    int rb = brow + wr + fi * 16 + lgrp * 4;
#pragma unroll
    for (int r = 0; r < 4; r++) {
      int row = rb + r;
      if (row < N_NODES) {
        float* op = out + (size_t)row * DIM + wc;
#pragma unroll
        for (int fj = 0; fj < 4; fj++)
          op[fj * 16 + l15] = acc[fi][fj][r] + bias[fj];
      }
    }
  }
}

// ---------------- fallback path (small ws): f32 atomic scatter ---------------
__global__ __launch_bounds__(256) void sage_scatter(
    const float* __restrict__ feat,
    const int* __restrict__ ei32,
    const long long* __restrict__ ei64,
    const unsigned* __restrict__ flag,
    float* __restrict__ agg,
    float* __restrict__ deg,
    int nWaves) {
  int wave = (blockIdx.x * blockDim.x + threadIdx.x) >> 6;
  int lane = threadIdx.x & 63;
  const bool i32 = (*flag != 0u);
  for (int e = wave; e < N_EDGES; e += nWaves) {
    int s, d;
    if (i32) { s = ei32[e];      d = ei32[N_EDGES + e]; }
    else     { s = (int)ei64[e]; d = (int)ei64[N_EDGES + e]; }
    float2 v = ((const float2*)(feat + (size_t)s * DIM))[lane];
    float* a = agg + (size_t)d * DIM + lane * 2;
    unsafeAtomicAdd(a, v.x);
    unsafeAtomicAdd(a + 1, v.y);
    if (lane == 0) unsafeAtomicAdd(deg + d, 1.0f);
  }
}

__global__ __launch_bounds__(256) void sage_norm(
    float* __restrict__ agg, const float* __restrict__ deg) {
  int i = blockIdx.x * blockDim.x + threadIdx.x;
  if (i >= N_NODES * DIM) return;
  int n = i >> 7;
  agg[i] *= 1.0f / fmaxf(deg[n], 1.0f);
}

extern "C" void kernel_launch(void* const* d_in, const int* in_sizes, int n_in,
                              void* d_out, int out_size, void* d_ws, size_t ws_size,
                              hipStream_t stream) {
  const float* feat = (const float*)d_in[0];
  const int* ei32 = (const int*)d_in[1];
  const long long* ei64 = (const long long*)d_in[1];
  const unsigned* eiw = (const unsigned*)d_in[1];
  const float* Wl = (const float*)d_in[2];
  const float* bl = (const float*)d_in[3];
  const float* Wr = (const float*)d_in[4];
  float* out = (float*)d_out;

  const size_t needPull = (16 + (size_t)N_NODES + (size_t)N_NODES * PAD) * 4
                        + (size_t)N_NODES * DIM * 4;

  const int gblocks = (N_NODES + GBM - 1) / GBM;   // 782

  if (ws_size >= needPull) {
    unsigned* flag = (unsigned*)d_ws;
    int* cursor = (int*)d_ws + 16;
    int* adj = cursor + N_NODES;
    float* agg = (float*)(adj + (size_t)N_NODES * PAD);
    hipMemsetAsync(d_ws, 0, (16 + (size_t)N_NODES) * 4, stream);
    detect_kernel<<<1, 256, 0, stream>>>(eiw, flag);
    sage_fill<<<(N_EDGES + 255) / 256, 256, 0, stream>>>(ei32, ei64, flag, cursor, adj);
    sage_pull<<<(N_NODES + 7) / 8, 256, 0, stream>>>(feat, adj, cursor, agg);
    sage_gemm_mfma<<<gblocks, 256, 0, stream>>>(feat, agg, Wl, bl, Wr, out);
  } else {
    unsigned* flag = (unsigned*)d_ws;
    float* agg = (float*)d_ws + 16;
    float* deg = agg + (size_t)N_NODES * DIM;
    hipMemsetAsync(d_ws, 0, (16 + (size_t)N_NODES * DIM + N_NODES) * 4, stream);
    detect_kernel<<<1, 256, 0, stream>>>(eiw, flag);
    const int sblocks = 2048;
    sage_scatter<<<sblocks, 256, 0, stream>>>(feat, ei32, ei64, flag, agg, deg, sblocks * 4);
    sage_norm<<<(N_NODES * DIM + 255) / 256, 256, 0, stream>>>(agg, deg);
    sage_gemm_mfma<<<gblocks, 256, 0, stream>>>(feat, agg, Wl, bl, Wr, out);
  }
}